// Round 8
// baseline (327.536 us; speedup 1.0000x reference)
//
#include <hip/hip_runtime.h>

// NCC loss, fused single-kernel, v4 (latency-focused).
// Inputs y_true, y_pred: (2,1,160,192,160) FP32. Output: 1 FP32 scalar = -sum(cc).
// R7 diagnosis: all pipes idle (VALU 31%, LDS ~20%, HBM 19%, occ 39%) ->
// barrier/latency-bound per slice-round. v4: (1) CHUNK 40->20 => 1920 blocks,
// ~2x co-resident waves; (2) two slices per barrier round into double LDS
// buffers (2x MLP on global loads, half the barriers/slice).
#define ND 2
#define DD 160
#define HH 192
#define WW 160
#define HW (HH * WW)

constexpr int TW    = 16;          // output tile width
constexpr int TH    = 16;          // output tile height
constexpr int HLO   = TH + 8;      // 24 W-sum rows incl. H halo
constexpr int CHUNK = 20;          // output d's per block
constexpr int NCH   = DD / CHUNK;  // 8
constexpr int NSL   = CHUNK + 8;   // 28 slices per block
constexpr int NR    = NSL / 2;     // 14 rounds, 2 slices each

// 9-wide box sum sliding to 4 outputs; x[0..11] -> S[0..3]
__device__ __forceinline__ void slide4(const float x[12], float S[4]) {
    float f = ((x[0] + x[1]) + (x[2] + x[3]))
            + ((x[4] + x[5]) + (x[6] + x[7])) + x[8];
    S[0] = f;
    f += x[9]  - x[0]; S[1] = f;
    f += x[10] - x[1]; S[2] = f;
    f += x[11] - x[2]; S[3] = f;
}

__global__ __launch_bounds__(256, 6)
void ncc_fused(const float* __restrict__ I, const float* __restrict__ J,
               float* __restrict__ outp)
{
    __shared__ float4 sws[2][HLO][TW + 1];  // fields (I,J,II,JJ), per pair-slice
    __shared__ float  sw4[2][HLO][TW + 1];  // field IJ
    __shared__ float  wred[4];

    const int tid  = threadIdx.x;
    const int w0   = blockIdx.x * TW;
    const int h0   = blockIdx.y * TH;
    const int z    = blockIdx.z;            // n * NCH + chunk
    const int n    = z / NCH;
    const int d0   = (z % NCH) * CHUNK;
    const int lane = tid & 63, wid = tid >> 6;
    const int oh   = tid >> 4, ow = tid & 15;   // stage-B output pixel

    // stage-A job constants: 192 jobs = pair-slice(2) x row(24) x wgroup(4)
    const bool ajob = (tid < 192);
    const int  sl   = tid / 96;             // which slice of the pair
    const int  rj   = tid - sl * 96;
    const int  arow = rj >> 2, awg = rj & 3;
    const int  agh  = h0 + arow - 4;
    const int  agws = w0 + awg * 4 - 4;     // aligned start of 12-float window
    const bool ahok = (agh >= 0) && (agh < HH);

    float rbuf[5][9];
    #pragma unroll
    for (int p = 0; p < 5; ++p)
        #pragma unroll
        for (int q = 0; q < 9; ++q) rbuf[p][q] = 0.f;
    float run0 = 0.f, run1 = 0.f, run2 = 0.f, run3 = 0.f, run4 = 0.f;
    float acc = 0.f;
    const float inv = 1.0f / 729.0f;

    #pragma unroll 1
    for (int g = 0; g < 2; ++g) {          // 2 x 9 rounds = 18 >= NR
        #pragma unroll
        for (int r = 0; r < 9; ++r) {      // fully unrolled: static ring slots
            const int rr = g * 9 + r;
            if (rr < NR) {
                const int s0  = 2 * rr;     // this round handles slices s0, s0+1
                const int dd0 = d0 - 4 + s0;

                // ---- stage A: both slices' W-sum fields -> LDS ----
                if (ajob) {
                    const int dd = dd0 + sl;
                    if (dd >= 0 && dd < DD) {
                        float a[12], b[12];
                        const int rbase = (n * DD + dd) * HW + agh * WW;
                        #pragma unroll
                        for (int c = 0; c < 3; ++c) {
                            const int gw = agws + 4 * c;
                            float4 va = make_float4(0.f, 0.f, 0.f, 0.f), vb = va;
                            if (ahok && gw >= 0 && gw < WW) {
                                va = *(const float4*)(I + rbase + gw);
                                vb = *(const float4*)(J + rbase + gw);
                            }
                            *(float4*)&a[4 * c] = va;
                            *(float4*)&b[4 * c] = vb;
                        }
                        float S0[4], S1[4], S2[4], S3[4], S4[4], f[12];
                        slide4(a, S0);
                        slide4(b, S1);
                        #pragma unroll
                        for (int i = 0; i < 12; ++i) f[i] = a[i] * a[i];
                        slide4(f, S2);
                        #pragma unroll
                        for (int i = 0; i < 12; ++i) f[i] = b[i] * b[i];
                        slide4(f, S3);
                        #pragma unroll
                        for (int i = 0; i < 12; ++i) f[i] = a[i] * b[i];
                        slide4(f, S4);
                        #pragma unroll
                        for (int t = 0; t < 4; ++t) {
                            sws[sl][arow][awg * 4 + t] =
                                make_float4(S0[t], S1[t], S2[t], S3[t]);
                            sw4[sl][arow][awg * 4 + t] = S4[t];
                        }
                    }
                }
                __syncthreads();

                // ---- stage B slice 0 ----
                {
                    float t0 = 0.f, t1 = 0.f, t2 = 0.f, t3 = 0.f, t4 = 0.f;
                    if (dd0 >= 0 && dd0 < DD) {
                        #pragma unroll
                        for (int q = 0; q < 9; ++q) {
                            const float4 v = sws[0][oh + q][ow];
                            t0 += v.x; t1 += v.y; t2 += v.z; t3 += v.w;
                            t4 += sw4[0][oh + q][ow];
                        }
                    }
                    const int jj = (2 * r) % 9;       // == s0 % 9 (18g drops out)
                    run0 += t0 - rbuf[0][jj]; rbuf[0][jj] = t0;
                    run1 += t1 - rbuf[1][jj]; rbuf[1][jj] = t1;
                    run2 += t2 - rbuf[2][jj]; rbuf[2][jj] = t2;
                    run3 += t3 - rbuf[3][jj]; rbuf[3][jj] = t3;
                    run4 += t4 - rbuf[4][jj]; rbuf[4][jj] = t4;
                    if (s0 >= 8) {
                        const float uI = run0 * inv, uJ = run1 * inv;
                        const float cross = run4 - uI * run1;
                        const float Iv = fmaxf(run2 - uI * run0, 1e-5f);
                        const float Jv = fmaxf(run3 - uJ * run1, 1e-5f);
                        acc += cross * cross / (Iv * Jv + 1e-5f);
                    }
                }
                // ---- stage B slice 1 ----
                {
                    const int dd1 = dd0 + 1, s1 = s0 + 1;
                    float t0 = 0.f, t1 = 0.f, t2 = 0.f, t3 = 0.f, t4 = 0.f;
                    if (dd1 >= 0 && dd1 < DD) {
                        #pragma unroll
                        for (int q = 0; q < 9; ++q) {
                            const float4 v = sws[1][oh + q][ow];
                            t0 += v.x; t1 += v.y; t2 += v.z; t3 += v.w;
                            t4 += sw4[1][oh + q][ow];
                        }
                    }
                    const int jj = (2 * r + 1) % 9;   // == s1 % 9
                    run0 += t0 - rbuf[0][jj]; rbuf[0][jj] = t0;
                    run1 += t1 - rbuf[1][jj]; rbuf[1][jj] = t1;
                    run2 += t2 - rbuf[2][jj]; rbuf[2][jj] = t2;
                    run3 += t3 - rbuf[3][jj]; rbuf[3][jj] = t3;
                    run4 += t4 - rbuf[4][jj]; rbuf[4][jj] = t4;
                    if (s1 >= 8) {
                        const float uI = run0 * inv, uJ = run1 * inv;
                        const float cross = run4 - uI * run1;
                        const float Iv = fmaxf(run2 - uI * run0, 1e-5f);
                        const float Jv = fmaxf(run3 - uJ * run1, 1e-5f);
                        acc += cross * cross / (Iv * Jv + 1e-5f);
                    }
                }
                __syncthreads();   // protect sws/sw4 before next round's stage A
            }
        }
    }

    // ---- block reduction, one fp32 atomic per block ----
    #pragma unroll
    for (int off = 32; off > 0; off >>= 1)
        acc += __shfl_down(acc, off, 64);
    if (lane == 0) wred[wid] = acc;
    __syncthreads();
    if (tid == 0)
        atomicAdd(outp, -(wred[0] + wred[1] + wred[2] + wred[3]));
}

extern "C" void kernel_launch(void* const* d_in, const int* in_sizes, int n_in,
                              void* d_out, int out_size, void* d_ws, size_t ws_size,
                              hipStream_t stream)
{
    const float* I = (const float*)d_in[0];   // y_true
    const float* J = (const float*)d_in[1];   // y_pred
    float* out = (float*)d_out;

    hipMemsetAsync(out, 0, sizeof(float), stream);

    dim3 grid(WW / TW, HH / TH, ND * NCH);    // 10 x 12 x 16 = 1920 blocks
    ncc_fused<<<grid, 256, 0, stream>>>(I, J, out);
}

// Round 9
// 216.037 us; speedup vs baseline: 1.5161x; 1.5161x over previous
//
#include <hip/hip_runtime.h>

// NCC loss, fused single-kernel, v5 = v4 minus the spill bug.
// Inputs y_true, y_pred: (2,1,160,192,160) FP32. Output: 1 FP32 scalar = -sum(cc).
// R8 post-mortem: __launch_bounds__(256,6) squeezed VGPR to 40 -> the 45-reg
// D-ring spilled to scratch (WRITE_SIZE 30KB->340MB, FETCH +240MB, kernel went
// HBM-bound on spill traffic at 3.07 TB/s ~= 261us). v5: bounds (256,4) so the
// ring stays in registers; keep CHUNK=20 (1920 blocks) + 2-slice rounds.
#define ND 2
#define DD 160
#define HH 192
#define WW 160
#define HW (HH * WW)

constexpr int TW    = 16;          // output tile width
constexpr int TH    = 16;          // output tile height
constexpr int HLO   = TH + 8;      // 24 W-sum rows incl. H halo
constexpr int CHUNK = 20;          // output d's per block
constexpr int NCH   = DD / CHUNK;  // 8
constexpr int NSL   = CHUNK + 8;   // 28 slices per block
constexpr int NR    = NSL / 2;     // 14 rounds, 2 slices each

// 9-wide box sum sliding to 4 outputs; x[0..11] -> S[0..3]
__device__ __forceinline__ void slide4(const float x[12], float S[4]) {
    float f = ((x[0] + x[1]) + (x[2] + x[3]))
            + ((x[4] + x[5]) + (x[6] + x[7])) + x[8];
    S[0] = f;
    f += x[9]  - x[0]; S[1] = f;
    f += x[10] - x[1]; S[2] = f;
    f += x[11] - x[2]; S[3] = f;
}

__global__ __launch_bounds__(256, 4)
void ncc_fused(const float* __restrict__ I, const float* __restrict__ J,
               float* __restrict__ outp)
{
    __shared__ float4 sws[2][HLO][TW + 1];  // fields (I,J,II,JJ), per pair-slice
    __shared__ float  sw4[2][HLO][TW + 1];  // field IJ
    __shared__ float  wred[4];

    const int tid  = threadIdx.x;
    const int w0   = blockIdx.x * TW;
    const int h0   = blockIdx.y * TH;
    const int z    = blockIdx.z;            // n * NCH + chunk
    const int n    = z / NCH;
    const int d0   = (z % NCH) * CHUNK;
    const int lane = tid & 63, wid = tid >> 6;
    const int oh   = tid >> 4, ow = tid & 15;   // stage-B output pixel

    // stage-A job constants: 192 jobs = pair-slice(2) x row(24) x wgroup(4)
    const bool ajob = (tid < 192);
    const int  sl   = tid / 96;             // which slice of the pair
    const int  rj   = tid - sl * 96;
    const int  arow = rj >> 2, awg = rj & 3;
    const int  agh  = h0 + arow - 4;
    const int  agws = w0 + awg * 4 - 4;     // aligned start of 12-float window
    const bool ahok = (agh >= 0) && (agh < HH);

    float rbuf[5][9];
    #pragma unroll
    for (int p = 0; p < 5; ++p)
        #pragma unroll
        for (int q = 0; q < 9; ++q) rbuf[p][q] = 0.f;
    float run0 = 0.f, run1 = 0.f, run2 = 0.f, run3 = 0.f, run4 = 0.f;
    float acc = 0.f;
    const float inv = 1.0f / 729.0f;

    #pragma unroll 1
    for (int g = 0; g < 2; ++g) {          // 2 x 9 rounds = 18 >= NR
        #pragma unroll
        for (int r = 0; r < 9; ++r) {      // fully unrolled: static ring slots
            const int rr = g * 9 + r;
            if (rr < NR) {
                const int s0  = 2 * rr;     // this round handles slices s0, s0+1
                const int dd0 = d0 - 4 + s0;

                // ---- stage A: both slices' W-sum fields -> LDS ----
                if (ajob) {
                    const int dd = dd0 + sl;
                    if (dd >= 0 && dd < DD) {
                        float a[12], b[12];
                        const int rbase = (n * DD + dd) * HW + agh * WW;
                        #pragma unroll
                        for (int c = 0; c < 3; ++c) {
                            const int gw = agws + 4 * c;
                            float4 va = make_float4(0.f, 0.f, 0.f, 0.f), vb = va;
                            if (ahok && gw >= 0 && gw < WW) {
                                va = *(const float4*)(I + rbase + gw);
                                vb = *(const float4*)(J + rbase + gw);
                            }
                            *(float4*)&a[4 * c] = va;
                            *(float4*)&b[4 * c] = vb;
                        }
                        float S0[4], S1[4], S2[4], S3[4], S4[4], f[12];
                        slide4(a, S0);
                        slide4(b, S1);
                        #pragma unroll
                        for (int i = 0; i < 12; ++i) f[i] = a[i] * a[i];
                        slide4(f, S2);
                        #pragma unroll
                        for (int i = 0; i < 12; ++i) f[i] = b[i] * b[i];
                        slide4(f, S3);
                        #pragma unroll
                        for (int i = 0; i < 12; ++i) f[i] = a[i] * b[i];
                        slide4(f, S4);
                        #pragma unroll
                        for (int t = 0; t < 4; ++t) {
                            sws[sl][arow][awg * 4 + t] =
                                make_float4(S0[t], S1[t], S2[t], S3[t]);
                            sw4[sl][arow][awg * 4 + t] = S4[t];
                        }
                    }
                }
                __syncthreads();

                // ---- stage B slice 0 ----
                {
                    float t0 = 0.f, t1 = 0.f, t2 = 0.f, t3 = 0.f, t4 = 0.f;
                    if (dd0 >= 0 && dd0 < DD) {
                        #pragma unroll
                        for (int q = 0; q < 9; ++q) {
                            const float4 v = sws[0][oh + q][ow];
                            t0 += v.x; t1 += v.y; t2 += v.z; t3 += v.w;
                            t4 += sw4[0][oh + q][ow];
                        }
                    }
                    const int jj = (2 * r) % 9;       // == s0 % 9 (18g drops out)
                    run0 += t0 - rbuf[0][jj]; rbuf[0][jj] = t0;
                    run1 += t1 - rbuf[1][jj]; rbuf[1][jj] = t1;
                    run2 += t2 - rbuf[2][jj]; rbuf[2][jj] = t2;
                    run3 += t3 - rbuf[3][jj]; rbuf[3][jj] = t3;
                    run4 += t4 - rbuf[4][jj]; rbuf[4][jj] = t4;
                    if (s0 >= 8) {
                        const float uI = run0 * inv, uJ = run1 * inv;
                        const float cross = run4 - uI * run1;
                        const float Iv = fmaxf(run2 - uI * run0, 1e-5f);
                        const float Jv = fmaxf(run3 - uJ * run1, 1e-5f);
                        acc += cross * cross / (Iv * Jv + 1e-5f);
                    }
                }
                // ---- stage B slice 1 ----
                {
                    const int dd1 = dd0 + 1, s1 = s0 + 1;
                    float t0 = 0.f, t1 = 0.f, t2 = 0.f, t3 = 0.f, t4 = 0.f;
                    if (dd1 >= 0 && dd1 < DD) {
                        #pragma unroll
                        for (int q = 0; q < 9; ++q) {
                            const float4 v = sws[1][oh + q][ow];
                            t0 += v.x; t1 += v.y; t2 += v.z; t3 += v.w;
                            t4 += sw4[1][oh + q][ow];
                        }
                    }
                    const int jj = (2 * r + 1) % 9;   // == s1 % 9
                    run0 += t0 - rbuf[0][jj]; rbuf[0][jj] = t0;
                    run1 += t1 - rbuf[1][jj]; rbuf[1][jj] = t1;
                    run2 += t2 - rbuf[2][jj]; rbuf[2][jj] = t2;
                    run3 += t3 - rbuf[3][jj]; rbuf[3][jj] = t3;
                    run4 += t4 - rbuf[4][jj]; rbuf[4][jj] = t4;
                    if (s1 >= 8) {
                        const float uI = run0 * inv, uJ = run1 * inv;
                        const float cross = run4 - uI * run1;
                        const float Iv = fmaxf(run2 - uI * run0, 1e-5f);
                        const float Jv = fmaxf(run3 - uJ * run1, 1e-5f);
                        acc += cross * cross / (Iv * Jv + 1e-5f);
                    }
                }
                __syncthreads();   // protect sws/sw4 before next round's stage A
            }
        }
    }

    // ---- block reduction, one fp32 atomic per block ----
    #pragma unroll
    for (int off = 32; off > 0; off >>= 1)
        acc += __shfl_down(acc, off, 64);
    if (lane == 0) wred[wid] = acc;
    __syncthreads();
    if (tid == 0)
        atomicAdd(outp, -(wred[0] + wred[1] + wred[2] + wred[3]));
}

extern "C" void kernel_launch(void* const* d_in, const int* in_sizes, int n_in,
                              void* d_out, int out_size, void* d_ws, size_t ws_size,
                              hipStream_t stream)
{
    const float* I = (const float*)d_in[0];   // y_true
    const float* J = (const float*)d_in[1];   // y_pred
    float* out = (float*)d_out;

    hipMemsetAsync(out, 0, sizeof(float), stream);

    dim3 grid(WW / TW, HH / TH, ND * NCH);    // 10 x 12 x 16 = 1920 blocks
    ncc_fused<<<grid, 256, 0, stream>>>(I, J, out);
}

// Round 10
// 205.502 us; speedup vs baseline: 1.5938x; 1.0513x over previous
//
#include <hip/hip_runtime.h>
#include <hip/hip_fp16.h>

// NCC loss, v6: two-pass via workspace with centered-fp16 intermediates.
// Inputs y_true, y_pred: (2,1,160,192,160) FP32. Output: 1 FP32 scalar = -sum(cc).
// R5-R9 post-mortem: all fused variants plateau at ~133us (2 barriers/slice x
// ~3 resident blocks/CU; the 45-reg D-ring forbids higher occupancy w/o spills).
// v6: pass1 computes W+H box-sums of the five CENTERED products (Ic=I-0.5) and
// stores them fp16 (values O(1-40) -> 5e-4 rel err, <0.1% on cross; borders
// reconstructed exactly in pass2 via analytic in-bounds count cnt=cW*cH*cD).
// Pass2 streams D with a register ring: no LDS, no barriers, deep MLP.
// ws requirement: 5 * 9,830,400 * 2 B = 98.3 MB (R1 proved >=196 MB exists).
#define ND 2
#define DD 160
#define HH 192
#define WW 160
#define HW (HH * WW)
#define DHW (DD * HH * WW)
#define VOX (ND * DHW)          // 9,830,400 voxels per field

// ---------------------------------------------------------------------------
// Pass 1: per (n,d) slice, 32x8 output tile. Stage A (128 threads): W-sums of
// 5 centered products from global. Stage B (256 threads): 9 H-taps -> fp16.
// ---------------------------------------------------------------------------
constexpr int P1TW  = 32;
constexpr int P1TH  = 8;
constexpr int P1HLO = P1TH + 8;   // 16 rows incl. H halo

__device__ __forceinline__ void slide4(const float x[12], float S[4]) {
    float f = ((x[0] + x[1]) + (x[2] + x[3]))
            + ((x[4] + x[5]) + (x[6] + x[7])) + x[8];
    S[0] = f;
    f += x[9]  - x[0]; S[1] = f;
    f += x[10] - x[1]; S[2] = f;
    f += x[11] - x[2]; S[3] = f;
}

__global__ __launch_bounds__(256)
void ncc_pass1(const float* __restrict__ I, const float* __restrict__ J,
               __half* __restrict__ ws)
{
    __shared__ float4 sws[P1HLO][P1TW + 1];  // centered (I,J,II,JJ) W-sums
    __shared__ float  sw4[P1HLO][P1TW + 1];  // centered IJ W-sums

    const int tid = threadIdx.x;
    const int w0  = blockIdx.x * P1TW;       // 0..128
    const int h0  = blockIdx.y * P1TH;       // 0..184
    const int z   = blockIdx.z;              // n*DD + d, 0..319
    const int sbase = z * HW;

    // ---- stage A: 128 jobs = 16 rows x 8 groups of 4 outputs ----
    if (tid < 128) {
        const int arow = tid >> 3;           // 0..15
        const int ag   = tid & 7;            // 0..7
        const int agh  = h0 + arow - 4;
        const bool ahok = (agh >= 0) && (agh < HH);
        const int rbase = sbase + agh * WW;
        const int agws  = w0 + ag * 4 - 4;

        float a[12], b[12];
        #pragma unroll
        for (int c = 0; c < 3; ++c) {
            const int gw = agws + 4 * c;
            float4 va = make_float4(0.f, 0.f, 0.f, 0.f), vb = va;
            if (ahok && gw >= 0 && gw < WW) {
                va = *(const float4*)(I + rbase + gw);
                vb = *(const float4*)(J + rbase + gw);
                va.x -= 0.5f; va.y -= 0.5f; va.z -= 0.5f; va.w -= 0.5f;
                vb.x -= 0.5f; vb.y -= 0.5f; vb.z -= 0.5f; vb.w -= 0.5f;
            }
            *(float4*)&a[4 * c] = va;
            *(float4*)&b[4 * c] = vb;
        }
        float S0[4], S1[4], S2[4], S3[4], S4[4], f[12];
        slide4(a, S0);
        slide4(b, S1);
        #pragma unroll
        for (int i = 0; i < 12; ++i) f[i] = a[i] * a[i];
        slide4(f, S2);
        #pragma unroll
        for (int i = 0; i < 12; ++i) f[i] = b[i] * b[i];
        slide4(f, S3);
        #pragma unroll
        for (int i = 0; i < 12; ++i) f[i] = a[i] * b[i];
        slide4(f, S4);
        #pragma unroll
        for (int t = 0; t < 4; ++t) {
            sws[arow][ag * 4 + t] = make_float4(S0[t], S1[t], S2[t], S3[t]);
            sw4[arow][ag * 4 + t] = S4[t];
        }
    }
    __syncthreads();

    // ---- stage B: 9 H-taps per output pixel, store fp16 ----
    const int oh = tid >> 5;                 // 0..7
    const int ow = tid & 31;                 // 0..31
    float t0 = 0.f, t1 = 0.f, t2 = 0.f, t3 = 0.f, t4 = 0.f;
    #pragma unroll
    for (int q = 0; q < 9; ++q) {
        const float4 v = sws[oh + q][ow];
        t0 += v.x; t1 += v.y; t2 += v.z; t3 += v.w;
        t4 += sw4[oh + q][ow];
    }
    const int g = sbase + (h0 + oh) * WW + (w0 + ow);
    ws[0 * VOX + g] = __float2half(t0);
    ws[1 * VOX + g] = __float2half(t1);
    ws[2 * VOX + g] = __float2half(t2);
    ws[3 * VOX + g] = __float2half(t3);
    ws[4 * VOX + g] = __float2half(t4);
}

// ---------------------------------------------------------------------------
// Pass 2: per (n,h,w) column, stream D with a 9-slot register ring. No LDS,
// no barriers. Reconstruct uncentered sums via cnt, cc, atomic reduce.
// ---------------------------------------------------------------------------
constexpr int P2CH = 40;                    // output d's per block
constexpr int P2NS = P2CH + 8;              // 48 slices streamed

__global__ __launch_bounds__(256)
void ncc_pass2(const __half* __restrict__ ws, float* __restrict__ outp)
{
    const int col = blockIdx.x * 256 + threadIdx.x;   // 0..61439
    const int d0  = blockIdx.y * P2CH;
    const int n   = col / HW;
    const int rem = col - n * HW;
    const int h   = rem / WW;
    const int w   = rem - h * WW;
    const int base = n * DHW + rem;

    const float cW = (float)(min(w + 4, WW - 1) - max(w - 4, 0) + 1);
    const float cH = (float)(min(h + 4, HH - 1) - max(h - 4, 0) + 1);
    const float cHW = cW * cH;

    float ring[5][9];
    #pragma unroll
    for (int p = 0; p < 5; ++p)
        #pragma unroll
        for (int q = 0; q < 9; ++q) ring[p][q] = 0.f;
    float run0 = 0.f, run1 = 0.f, run2 = 0.f, run3 = 0.f, run4 = 0.f;
    float acc = 0.f;
    const float inv = 1.0f / 729.0f;

    #pragma unroll 1
    for (int g = 0; g < 6; ++g) {           // 6 x 9 = 54 >= P2NS
        #pragma unroll
        for (int jj = 0; jj < 9; ++jj) {
            const int s = g * 9 + jj;
            if (s < P2NS) {
                const int dd = d0 - 4 + s;
                float v0 = 0.f, v1 = 0.f, v2 = 0.f, v3 = 0.f, v4 = 0.f;
                if (dd >= 0 && dd < DD) {
                    const int a = base + dd * HW;
                    v0 = __half2float(ws[0 * VOX + a]);
                    v1 = __half2float(ws[1 * VOX + a]);
                    v2 = __half2float(ws[2 * VOX + a]);
                    v3 = __half2float(ws[3 * VOX + a]);
                    v4 = __half2float(ws[4 * VOX + a]);
                }
                run0 += v0 - ring[0][jj]; ring[0][jj] = v0;
                run1 += v1 - ring[1][jj]; ring[1][jj] = v1;
                run2 += v2 - ring[2][jj]; ring[2][jj] = v2;
                run3 += v3 - ring[3][jj]; ring[3][jj] = v3;
                run4 += v4 - ring[4][jj]; ring[4][jj] = v4;

                if (s >= 8) {
                    const int d = d0 + s - 8;
                    const float cD  = (float)(min(d + 4, DD - 1) - max(d - 4, 0) + 1);
                    const float cnt = cHW * cD;
                    // reconstruct uncentered box sums (exact algebra)
                    const float Is  = run0 + 0.5f * cnt;
                    const float Js  = run1 + 0.5f * cnt;
                    const float I2  = run2 + run0 + 0.25f * cnt;
                    const float J2  = run3 + run1 + 0.25f * cnt;
                    const float IJ  = run4 + 0.5f * (run0 + run1) + 0.25f * cnt;
                    const float uI = Is * inv, uJ = Js * inv;
                    const float cross = IJ - uI * Js;
                    const float Iv = fmaxf(I2 - uI * Is, 1e-5f);
                    const float Jv = fmaxf(J2 - uJ * Js, 1e-5f);
                    acc += cross * cross / (Iv * Jv + 1e-5f);
                }
            }
        }
    }

    // ---- block reduction, one fp32 atomic per block ----
    __shared__ float wred[4];
    #pragma unroll
    for (int off = 32; off > 0; off >>= 1)
        acc += __shfl_down(acc, off, 64);
    const int lane = threadIdx.x & 63, wid = threadIdx.x >> 6;
    if (lane == 0) wred[wid] = acc;
    __syncthreads();
    if (threadIdx.x == 0)
        atomicAdd(outp, -(wred[0] + wred[1] + wred[2] + wred[3]));
}

// ---------------------------------------------------------------------------
// Fallback (ws too small): R9's fused kernel, known-passing at ~134 us.
// ---------------------------------------------------------------------------
constexpr int FTW = 16, FTH = 16, FHLO = FTH + 8;
constexpr int FCH = 20, FNCH = DD / FCH, FNSL = FCH + 8, FNR = FNSL / 2;

__global__ __launch_bounds__(256, 4)
void ncc_fused(const float* __restrict__ I, const float* __restrict__ J,
               float* __restrict__ outp)
{
    __shared__ float4 sws[2][FHLO][FTW + 1];
    __shared__ float  sw4[2][FHLO][FTW + 1];
    __shared__ float  wred[4];

    const int tid = threadIdx.x;
    const int w0 = blockIdx.x * FTW, h0 = blockIdx.y * FTH;
    const int z = blockIdx.z, n = z / FNCH, d0 = (z % FNCH) * FCH;
    const int lane = tid & 63, wid = tid >> 6;
    const int oh = tid >> 4, ow = tid & 15;
    const bool ajob = (tid < 192);
    const int sl = tid / 96, rj = tid - sl * 96;
    const int arow = rj >> 2, awg = rj & 3;
    const int agh = h0 + arow - 4, agws = w0 + awg * 4 - 4;
    const bool ahok = (agh >= 0) && (agh < HH);

    float rbuf[5][9];
    #pragma unroll
    for (int p = 0; p < 5; ++p)
        #pragma unroll
        for (int q = 0; q < 9; ++q) rbuf[p][q] = 0.f;
    float run0 = 0.f, run1 = 0.f, run2 = 0.f, run3 = 0.f, run4 = 0.f;
    float acc = 0.f;
    const float inv = 1.0f / 729.0f;

    #pragma unroll 1
    for (int g = 0; g < 2; ++g) {
        #pragma unroll
        for (int r = 0; r < 9; ++r) {
            const int rr = g * 9 + r;
            if (rr < FNR) {
                const int s0 = 2 * rr, dd0 = d0 - 4 + s0;
                if (ajob) {
                    const int dd = dd0 + sl;
                    if (dd >= 0 && dd < DD) {
                        float a[12], b[12];
                        const int rbase = (n * DD + dd) * HW + agh * WW;
                        #pragma unroll
                        for (int c = 0; c < 3; ++c) {
                            const int gw = agws + 4 * c;
                            float4 va = make_float4(0.f, 0.f, 0.f, 0.f), vb = va;
                            if (ahok && gw >= 0 && gw < WW) {
                                va = *(const float4*)(I + rbase + gw);
                                vb = *(const float4*)(J + rbase + gw);
                            }
                            *(float4*)&a[4 * c] = va;
                            *(float4*)&b[4 * c] = vb;
                        }
                        float S0[4], S1[4], S2[4], S3[4], S4[4], f[12];
                        slide4(a, S0);
                        slide4(b, S1);
                        #pragma unroll
                        for (int i = 0; i < 12; ++i) f[i] = a[i] * a[i];
                        slide4(f, S2);
                        #pragma unroll
                        for (int i = 0; i < 12; ++i) f[i] = b[i] * b[i];
                        slide4(f, S3);
                        #pragma unroll
                        for (int i = 0; i < 12; ++i) f[i] = a[i] * b[i];
                        slide4(f, S4);
                        #pragma unroll
                        for (int t = 0; t < 4; ++t) {
                            sws[sl][arow][awg * 4 + t] =
                                make_float4(S0[t], S1[t], S2[t], S3[t]);
                            sw4[sl][arow][awg * 4 + t] = S4[t];
                        }
                    }
                }
                __syncthreads();
                #pragma unroll
                for (int half = 0; half < 2; ++half) {
                    const int ddx = dd0 + half, sx = s0 + half;
                    float t0 = 0.f, t1 = 0.f, t2 = 0.f, t3 = 0.f, t4 = 0.f;
                    if (ddx >= 0 && ddx < DD) {
                        #pragma unroll
                        for (int q = 0; q < 9; ++q) {
                            const float4 v = sws[half][oh + q][ow];
                            t0 += v.x; t1 += v.y; t2 += v.z; t3 += v.w;
                            t4 += sw4[half][oh + q][ow];
                        }
                    }
                    const int jj = (2 * r + half) % 9;
                    run0 += t0 - rbuf[0][jj]; rbuf[0][jj] = t0;
                    run1 += t1 - rbuf[1][jj]; rbuf[1][jj] = t1;
                    run2 += t2 - rbuf[2][jj]; rbuf[2][jj] = t2;
                    run3 += t3 - rbuf[3][jj]; rbuf[3][jj] = t3;
                    run4 += t4 - rbuf[4][jj]; rbuf[4][jj] = t4;
                    if (sx >= 8) {
                        const float uI = run0 * inv, uJ = run1 * inv;
                        const float cross = run4 - uI * run1;
                        const float Iv = fmaxf(run2 - uI * run0, 1e-5f);
                        const float Jv = fmaxf(run3 - uJ * run1, 1e-5f);
                        acc += cross * cross / (Iv * Jv + 1e-5f);
                    }
                }
                __syncthreads();
            }
        }
    }
    #pragma unroll
    for (int off = 32; off > 0; off >>= 1)
        acc += __shfl_down(acc, off, 64);
    if (lane == 0) wred[wid] = acc;
    __syncthreads();
    if (tid == 0)
        atomicAdd(outp, -(wred[0] + wred[1] + wred[2] + wred[3]));
}

extern "C" void kernel_launch(void* const* d_in, const int* in_sizes, int n_in,
                              void* d_out, int out_size, void* d_ws, size_t ws_size,
                              hipStream_t stream)
{
    const float* I = (const float*)d_in[0];   // y_true
    const float* J = (const float*)d_in[1];   // y_pred
    float* out = (float*)d_out;

    hipMemsetAsync(out, 0, sizeof(float), stream);

    const size_t need = (size_t)5 * VOX * sizeof(__half);   // 98.3 MB
    if (ws_size >= need) {
        __half* ws = (__half*)d_ws;
        dim3 g1(WW / P1TW, HH / P1TH, ND * DD);   // 5 x 24 x 320 = 38400
        ncc_pass1<<<g1, 256, 0, stream>>>(I, J, ws);
        dim3 g2(ND * HW / 256, DD / P2CH);        // 240 x 4 = 960
        ncc_pass2<<<g2, 256, 0, stream>>>(ws, out);
    } else {
        dim3 grid(WW / FTW, HH / FTH, ND * FNCH); // 10 x 12 x 16
        ncc_fused<<<grid, 256, 0, stream>>>(I, J, out);
    }
}

// Round 11
// 187.457 us; speedup vs baseline: 1.7473x; 1.0963x over previous
//
#include <hip/hip_runtime.h>
#include <hip/hip_fp16.h>

// NCC loss, v7: two-pass, centered-fp16 intermediates (R10 passed, absmax 0).
// R10 counters: pass1 95us, occ 83%, HBM 39%, VALU 39% -> nothing saturated;
// FETCH 195MB = 2.5x halo over-fetch at 32x8 tiles. v7 pass1: 32x16 tiles
// (1.875x halo), stage-A on 192/256 threads, stage-B h-pair outputs (10 tap
// rows per 2 outputs instead of 18). pass2 unchanged.
#define ND 2
#define DD 160
#define HH 192
#define WW 160
#define HW (HH * WW)
#define DHW (DD * HH * WW)
#define VOX (ND * DHW)          // 9,830,400 voxels per field

__device__ __forceinline__ void slide4(const float x[12], float S[4]) {
    float f = ((x[0] + x[1]) + (x[2] + x[3]))
            + ((x[4] + x[5]) + (x[6] + x[7])) + x[8];
    S[0] = f;
    f += x[9]  - x[0]; S[1] = f;
    f += x[10] - x[1]; S[2] = f;
    f += x[11] - x[2]; S[3] = f;
}

// ---------------------------------------------------------------------------
// Pass 1: per (n,d) slice, 32x16 output tile. Stage A (192 threads): W-sums
// of 5 centered products from global. Stage B: h-pair outputs, fp16 stores.
// ---------------------------------------------------------------------------
constexpr int P1TW  = 32;
constexpr int P1TH  = 16;
constexpr int P1HLO = P1TH + 8;   // 24 rows incl. H halo

__global__ __launch_bounds__(256)
void ncc_pass1(const float* __restrict__ I, const float* __restrict__ J,
               __half* __restrict__ ws)
{
    __shared__ float4 sws[P1HLO][P1TW + 1];  // centered (I,J,II,JJ) W-sums
    __shared__ float  sw4[P1HLO][P1TW + 1];  // centered IJ W-sums

    const int tid = threadIdx.x;
    const int w0  = blockIdx.x * P1TW;       // 0..128
    const int h0  = blockIdx.y * P1TH;       // 0..176
    const int z   = blockIdx.z;              // n*DD + d, 0..319
    const int sbase = z * HW;

    // ---- stage A: 192 jobs = 24 rows x 8 groups of 4 outputs ----
    if (tid < 192) {
        const int arow = tid >> 3;           // 0..23
        const int ag   = tid & 7;            // 0..7
        const int agh  = h0 + arow - 4;
        const bool ahok = (agh >= 0) && (agh < HH);
        const int rbase = sbase + agh * WW;
        const int agws  = w0 + ag * 4 - 4;

        float a[12], b[12];
        #pragma unroll
        for (int c = 0; c < 3; ++c) {
            const int gw = agws + 4 * c;
            float4 va = make_float4(0.f, 0.f, 0.f, 0.f), vb = va;
            if (ahok && gw >= 0 && gw < WW) {
                va = *(const float4*)(I + rbase + gw);
                vb = *(const float4*)(J + rbase + gw);
                va.x -= 0.5f; va.y -= 0.5f; va.z -= 0.5f; va.w -= 0.5f;
                vb.x -= 0.5f; vb.y -= 0.5f; vb.z -= 0.5f; vb.w -= 0.5f;
            }
            *(float4*)&a[4 * c] = va;
            *(float4*)&b[4 * c] = vb;
        }
        float S0[4], S1[4], S2[4], S3[4], S4[4], f[12];
        slide4(a, S0);
        slide4(b, S1);
        #pragma unroll
        for (int i = 0; i < 12; ++i) f[i] = a[i] * a[i];
        slide4(f, S2);
        #pragma unroll
        for (int i = 0; i < 12; ++i) f[i] = b[i] * b[i];
        slide4(f, S3);
        #pragma unroll
        for (int i = 0; i < 12; ++i) f[i] = a[i] * b[i];
        slide4(f, S4);
        #pragma unroll
        for (int t = 0; t < 4; ++t) {
            sws[arow][ag * 4 + t] = make_float4(S0[t], S1[t], S2[t], S3[t]);
            sw4[arow][ag * 4 + t] = S4[t];
        }
    }
    __syncthreads();

    // ---- stage B: h-pair of outputs per thread, 10 tap rows, fp16 stores ----
    const int oh2 = tid >> 5;                // 0..7
    const int h   = oh2 * 2;
    const int ow  = tid & 31;                // 0..31
    float t0 = 0.f, t1 = 0.f, t2 = 0.f, t3 = 0.f, t4 = 0.f;
    float f0x, f0y, f0z, f0w, f04;           // first tap row (for the pair diff)
    {
        const float4 v = sws[h][ow];
        f0x = v.x; f0y = v.y; f0z = v.z; f0w = v.w;
        f04 = sw4[h][ow];
        t0 = v.x; t1 = v.y; t2 = v.z; t3 = v.w; t4 = f04;
    }
    #pragma unroll
    for (int q = 1; q < 9; ++q) {
        const float4 v = sws[h + q][ow];
        t0 += v.x; t1 += v.y; t2 += v.z; t3 += v.w;
        t4 += sw4[h + q][ow];
    }
    float u0, u1, u2, u3, u4;
    {
        const float4 v = sws[h + 9][ow];
        u0 = t0 + v.x - f0x;
        u1 = t1 + v.y - f0y;
        u2 = t2 + v.z - f0z;
        u3 = t3 + v.w - f0w;
        u4 = t4 + sw4[h + 9][ow] - f04;
    }
    const int g = sbase + (h0 + h) * WW + (w0 + ow);
    ws[0 * VOX + g] = __float2half(t0);
    ws[1 * VOX + g] = __float2half(t1);
    ws[2 * VOX + g] = __float2half(t2);
    ws[3 * VOX + g] = __float2half(t3);
    ws[4 * VOX + g] = __float2half(t4);
    ws[0 * VOX + g + WW] = __float2half(u0);
    ws[1 * VOX + g + WW] = __float2half(u1);
    ws[2 * VOX + g + WW] = __float2half(u2);
    ws[3 * VOX + g + WW] = __float2half(u3);
    ws[4 * VOX + g + WW] = __float2half(u4);
}

// ---------------------------------------------------------------------------
// Pass 2: per (n,h,w) column, stream D with a 9-slot register ring. No LDS,
// no barriers. Reconstruct uncentered sums via cnt, cc, atomic reduce.
// ---------------------------------------------------------------------------
constexpr int P2CH = 40;                    // output d's per block
constexpr int P2NS = P2CH + 8;              // 48 slices streamed

__global__ __launch_bounds__(256)
void ncc_pass2(const __half* __restrict__ ws, float* __restrict__ outp)
{
    const int col = blockIdx.x * 256 + threadIdx.x;   // 0..61439
    const int d0  = blockIdx.y * P2CH;
    const int n   = col / HW;
    const int rem = col - n * HW;
    const int h   = rem / WW;
    const int w   = rem - h * WW;
    const int base = n * DHW + rem;

    const float cW = (float)(min(w + 4, WW - 1) - max(w - 4, 0) + 1);
    const float cH = (float)(min(h + 4, HH - 1) - max(h - 4, 0) + 1);
    const float cHW = cW * cH;

    float ring[5][9];
    #pragma unroll
    for (int p = 0; p < 5; ++p)
        #pragma unroll
        for (int q = 0; q < 9; ++q) ring[p][q] = 0.f;
    float run0 = 0.f, run1 = 0.f, run2 = 0.f, run3 = 0.f, run4 = 0.f;
    float acc = 0.f;
    const float inv = 1.0f / 729.0f;

    #pragma unroll 1
    for (int g = 0; g < 6; ++g) {           // 6 x 9 = 54 >= P2NS
        #pragma unroll
        for (int jj = 0; jj < 9; ++jj) {
            const int s = g * 9 + jj;
            if (s < P2NS) {
                const int dd = d0 - 4 + s;
                float v0 = 0.f, v1 = 0.f, v2 = 0.f, v3 = 0.f, v4 = 0.f;
                if (dd >= 0 && dd < DD) {
                    const int a = base + dd * HW;
                    v0 = __half2float(ws[0 * VOX + a]);
                    v1 = __half2float(ws[1 * VOX + a]);
                    v2 = __half2float(ws[2 * VOX + a]);
                    v3 = __half2float(ws[3 * VOX + a]);
                    v4 = __half2float(ws[4 * VOX + a]);
                }
                run0 += v0 - ring[0][jj]; ring[0][jj] = v0;
                run1 += v1 - ring[1][jj]; ring[1][jj] = v1;
                run2 += v2 - ring[2][jj]; ring[2][jj] = v2;
                run3 += v3 - ring[3][jj]; ring[3][jj] = v3;
                run4 += v4 - ring[4][jj]; ring[4][jj] = v4;

                if (s >= 8) {
                    const int d = d0 + s - 8;
                    const float cD  = (float)(min(d + 4, DD - 1) - max(d - 4, 0) + 1);
                    const float cnt = cHW * cD;
                    // reconstruct uncentered box sums (exact algebra)
                    const float Is  = run0 + 0.5f * cnt;
                    const float Js  = run1 + 0.5f * cnt;
                    const float I2  = run2 + run0 + 0.25f * cnt;
                    const float J2  = run3 + run1 + 0.25f * cnt;
                    const float IJ  = run4 + 0.5f * (run0 + run1) + 0.25f * cnt;
                    const float uI = Is * inv, uJ = Js * inv;
                    const float cross = IJ - uI * Js;
                    const float Iv = fmaxf(I2 - uI * Is, 1e-5f);
                    const float Jv = fmaxf(J2 - uJ * Js, 1e-5f);
                    acc += cross * cross / (Iv * Jv + 1e-5f);
                }
            }
        }
    }

    // ---- block reduction, one fp32 atomic per block ----
    __shared__ float wred[4];
    #pragma unroll
    for (int off = 32; off > 0; off >>= 1)
        acc += __shfl_down(acc, off, 64);
    const int lane = threadIdx.x & 63, wid = threadIdx.x >> 6;
    if (lane == 0) wred[wid] = acc;
    __syncthreads();
    if (threadIdx.x == 0)
        atomicAdd(outp, -(wred[0] + wred[1] + wred[2] + wred[3]));
}

// ---------------------------------------------------------------------------
// Fallback (ws too small): R9's fused kernel, known-passing at ~134 us.
// ---------------------------------------------------------------------------
constexpr int FTW = 16, FTH = 16, FHLO = FTH + 8;
constexpr int FCH = 20, FNCH = DD / FCH, FNSL = FCH + 8, FNR = FNSL / 2;

__global__ __launch_bounds__(256, 4)
void ncc_fused(const float* __restrict__ I, const float* __restrict__ J,
               float* __restrict__ outp)
{
    __shared__ float4 sws[2][FHLO][FTW + 1];
    __shared__ float  sw4[2][FHLO][FTW + 1];
    __shared__ float  wred[4];

    const int tid = threadIdx.x;
    const int w0 = blockIdx.x * FTW, h0 = blockIdx.y * FTH;
    const int z = blockIdx.z, n = z / FNCH, d0 = (z % FNCH) * FCH;
    const int lane = tid & 63, wid = tid >> 6;
    const int oh = tid >> 4, ow = tid & 15;
    const bool ajob = (tid < 192);
    const int sl = tid / 96, rj = tid - sl * 96;
    const int arow = rj >> 2, awg = rj & 3;
    const int agh = h0 + arow - 4, agws = w0 + awg * 4 - 4;
    const bool ahok = (agh >= 0) && (agh < HH);

    float rbuf[5][9];
    #pragma unroll
    for (int p = 0; p < 5; ++p)
        #pragma unroll
        for (int q = 0; q < 9; ++q) rbuf[p][q] = 0.f;
    float run0 = 0.f, run1 = 0.f, run2 = 0.f, run3 = 0.f, run4 = 0.f;
    float acc = 0.f;
    const float inv = 1.0f / 729.0f;

    #pragma unroll 1
    for (int g = 0; g < 2; ++g) {
        #pragma unroll
        for (int r = 0; r < 9; ++r) {
            const int rr = g * 9 + r;
            if (rr < FNR) {
                const int s0 = 2 * rr, dd0 = d0 - 4 + s0;
                if (ajob) {
                    const int dd = dd0 + sl;
                    if (dd >= 0 && dd < DD) {
                        float a[12], b[12];
                        const int rbase = (n * DD + dd) * HW + agh * WW;
                        #pragma unroll
                        for (int c = 0; c < 3; ++c) {
                            const int gw = agws + 4 * c;
                            float4 va = make_float4(0.f, 0.f, 0.f, 0.f), vb = va;
                            if (ahok && gw >= 0 && gw < WW) {
                                va = *(const float4*)(I + rbase + gw);
                                vb = *(const float4*)(J + rbase + gw);
                            }
                            *(float4*)&a[4 * c] = va;
                            *(float4*)&b[4 * c] = vb;
                        }
                        float S0[4], S1[4], S2[4], S3[4], S4[4], f[12];
                        slide4(a, S0);
                        slide4(b, S1);
                        #pragma unroll
                        for (int i = 0; i < 12; ++i) f[i] = a[i] * a[i];
                        slide4(f, S2);
                        #pragma unroll
                        for (int i = 0; i < 12; ++i) f[i] = b[i] * b[i];
                        slide4(f, S3);
                        #pragma unroll
                        for (int i = 0; i < 12; ++i) f[i] = a[i] * b[i];
                        slide4(f, S4);
                        #pragma unroll
                        for (int t = 0; t < 4; ++t) {
                            sws[sl][arow][awg * 4 + t] =
                                make_float4(S0[t], S1[t], S2[t], S3[t]);
                            sw4[sl][arow][awg * 4 + t] = S4[t];
                        }
                    }
                }
                __syncthreads();
                #pragma unroll
                for (int half = 0; half < 2; ++half) {
                    const int ddx = dd0 + half, sx = s0 + half;
                    float t0 = 0.f, t1 = 0.f, t2 = 0.f, t3 = 0.f, t4 = 0.f;
                    if (ddx >= 0 && ddx < DD) {
                        #pragma unroll
                        for (int q = 0; q < 9; ++q) {
                            const float4 v = sws[half][oh + q][ow];
                            t0 += v.x; t1 += v.y; t2 += v.z; t3 += v.w;
                            t4 += sw4[half][oh + q][ow];
                        }
                    }
                    const int jj = (2 * r + half) % 9;
                    run0 += t0 - rbuf[0][jj]; rbuf[0][jj] = t0;
                    run1 += t1 - rbuf[1][jj]; rbuf[1][jj] = t1;
                    run2 += t2 - rbuf[2][jj]; rbuf[2][jj] = t2;
                    run3 += t3 - rbuf[3][jj]; rbuf[3][jj] = t3;
                    run4 += t4 - rbuf[4][jj]; rbuf[4][jj] = t4;
                    if (sx >= 8) {
                        const float uI = run0 * inv, uJ = run1 * inv;
                        const float cross = run4 - uI * run1;
                        const float Iv = fmaxf(run2 - uI * run0, 1e-5f);
                        const float Jv = fmaxf(run3 - uJ * run1, 1e-5f);
                        acc += cross * cross / (Iv * Jv + 1e-5f);
                    }
                }
                __syncthreads();
            }
        }
    }
    #pragma unroll
    for (int off = 32; off > 0; off >>= 1)
        acc += __shfl_down(acc, off, 64);
    if (lane == 0) wred[wid] = acc;
    __syncthreads();
    if (tid == 0)
        atomicAdd(outp, -(wred[0] + wred[1] + wred[2] + wred[3]));
}

extern "C" void kernel_launch(void* const* d_in, const int* in_sizes, int n_in,
                              void* d_out, int out_size, void* d_ws, size_t ws_size,
                              hipStream_t stream)
{
    const float* I = (const float*)d_in[0];   // y_true
    const float* J = (const float*)d_in[1];   // y_pred
    float* out = (float*)d_out;

    hipMemsetAsync(out, 0, sizeof(float), stream);

    const size_t need = (size_t)5 * VOX * sizeof(__half);   // 98.3 MB
    if (ws_size >= need) {
        __half* ws = (__half*)d_ws;
        dim3 g1(WW / P1TW, HH / P1TH, ND * DD);   // 5 x 12 x 320 = 19200
        ncc_pass1<<<g1, 256, 0, stream>>>(I, J, ws);
        dim3 g2(ND * HW / 256, DD / P2CH);        // 240 x 4 = 960
        ncc_pass2<<<g2, 256, 0, stream>>>(ws, out);
    } else {
        dim3 grid(WW / FTW, HH / FTH, ND * FNCH); // 10 x 12 x 16
        ncc_fused<<<grid, 256, 0, stream>>>(I, J, out);
    }
}